// Round 4
// baseline (514.415 us; speedup 1.0000x reference)
//
#include <hip/hip_runtime.h>

#define N_NODES 50000
#define N_EDGES 1000000
#define EMB     64
#define HID     128
#define NLAYER  3
#define NGRAPH  250
#define XFD     7
#define EFD     5
#define BN_EPS  1e-5f
#define NB_SCAN 196  // ceil(50000/256)

__device__ __forceinline__ void atomAddF(float* p, float v) {
    __hip_atomic_fetch_add(p, v, __ATOMIC_RELAXED, __HIP_MEMORY_SCOPE_AGENT);
}

// h = x @ xW + xb
__global__ void k_input(const float* __restrict__ x, const float* __restrict__ xW,
                        const float* __restrict__ xb, float* __restrict__ h) {
    int gid = blockIdx.x * 256 + threadIdx.x;
    if (gid >= N_NODES * EMB) return;
    int n = gid >> 6, f = gid & 63;
    float acc = xb[f];
#pragma unroll
    for (int k = 0; k < XFD; ++k) acc = fmaf(x[n * XFD + k], xW[k * EMB + f], acc);
    h[gid] = acc;
}

// indegree histogram (int atomics only)
__global__ void k_hist(const int* __restrict__ dst, int* __restrict__ deg) {
    int i = blockIdx.x * 256 + threadIdx.x;
    if (i >= N_EDGES) return;
    atomicAdd(&deg[dst[i]], 1);
}

// ---- 3-phase multi-block exclusive scan ----
__global__ __launch_bounds__(256) void k_scanA(const int* __restrict__ deg,
                                               int* __restrict__ bsum) {
    int tid = threadIdx.x, lane = tid & 63, wid = tid >> 6;
    int i = blockIdx.x * 256 + tid;
    int v = (i < N_NODES) ? deg[i] : 0;
#pragma unroll
    for (int off = 32; off; off >>= 1) v += __shfl_down(v, off);
    __shared__ int ws[4];
    if (lane == 0) ws[wid] = v;
    __syncthreads();
    if (tid == 0) bsum[blockIdx.x] = ws[0] + ws[1] + ws[2] + ws[3];
}

__global__ __launch_bounds__(256) void k_scanB(const int* __restrict__ bsum,
                                               int* __restrict__ boff) {
    int tid = threadIdx.x, lane = tid & 63, wid = tid >> 6;
    int v = (tid < NB_SCAN) ? bsum[tid] : 0;
    int x = v;
#pragma unroll
    for (int off = 1; off < 64; off <<= 1) {
        int y = __shfl_up(x, off);
        if (lane >= off) x += y;
    }
    __shared__ int wtot[4];
    if (lane == 63) wtot[wid] = x;
    __syncthreads();
    int woff = 0;
    for (int w = 0; w < wid; ++w) woff += wtot[w];
    if (tid < NB_SCAN) boff[tid] = woff + x - v;  // exclusive
}

__global__ __launch_bounds__(256) void k_scanC(const int* __restrict__ deg,
                                               const int* __restrict__ boff,
                                               int* __restrict__ rowstart,
                                               int* __restrict__ cursor) {
    int tid = threadIdx.x, lane = tid & 63, wid = tid >> 6;
    int i = blockIdx.x * 256 + tid;
    int v = (i < N_NODES) ? deg[i] : 0;
    int x = v;
#pragma unroll
    for (int off = 1; off < 64; off <<= 1) {
        int y = __shfl_up(x, off);
        if (lane >= off) x += y;
    }
    __shared__ int wtot[4];
    if (lane == 63) wtot[wid] = x;
    __syncthreads();
    int woff = boff[blockIdx.x];
    for (int w = 0; w < wid; ++w) woff += wtot[w];
    int excl = woff + x - v;
    if (i < N_NODES) {
        rowstart[i] = excl;
        cursor[i] = excl;
        if (i == N_NODES - 1) rowstart[N_NODES] = excl + v;
    }
}

// scatter packed (src, eid) — ONE 8B store per edge (R3: two 4B scatters gave
// 98MB writeback; packing halves scattered-line touches)
__global__ void k_fill(const int* __restrict__ src, const int* __restrict__ dst,
                       int* __restrict__ cursor, int2* __restrict__ csr2) {
    int i = blockIdx.x * 256 + threadIdx.x;
    if (i >= N_EDGES) return;
    int d = dst[i];
    int p = atomicAdd(&cursor[d], 1);
    csr2[p] = make_int2(src[i], i);
}

// aggE[n] = sum of ea over in-edges (via .y), AND compact .x into permanent csr
__global__ __launch_bounds__(256) void k_aggE(const int* __restrict__ rowstart,
                                              const int2* __restrict__ csr2,
                                              const float* __restrict__ ea,
                                              float* __restrict__ aggE,
                                              int* __restrict__ csr) {
    int wid = (blockIdx.x * 256 + threadIdx.x) >> 6;
    int lane = threadIdx.x & 63;
    if (wid >= N_NODES) return;
    int j0 = rowstart[wid], j1 = rowstart[wid + 1];
    float s0 = 0.f, s1 = 0.f, s2 = 0.f, s3 = 0.f, s4 = 0.f;
    for (int j = j0 + lane; j < j1; j += 64) {
        int2 v = csr2[j];
        csr[j] = v.x;
        const float* p = ea + v.y * EFD;
        s0 += p[0]; s1 += p[1]; s2 += p[2]; s3 += p[3]; s4 += p[4];
    }
#pragma unroll
    for (int off = 32; off; off >>= 1) {
        s0 += __shfl_down(s0, off);
        s1 += __shfl_down(s1, off);
        s2 += __shfl_down(s2, off);
        s3 += __shfl_down(s3, off);
        s4 += __shfl_down(s4, off);
    }
    if (lane == 0) {
        float* o = aggE + wid * EFD;
        o[0] = s0; o[1] = s1; o[2] = s2; o[3] = s3; o[4] = s4;
    }
}

// agg[n] = h[n] + (8*eW[0]+eb) + sum_in h[src] + aggE[n]@eW + deg*eb
// wave/node, float4 gathers, 4 edges in flight (lg=edge slot, lq=float4 idx):
// 4x fewer issue slots + 4x shorter dependent chain vs scalar-per-edge (R3).
__global__ __launch_bounds__(256) void k_agg(const float* __restrict__ h,
                                             float* __restrict__ agg,
                                             const int* __restrict__ rowstart,
                                             const int* __restrict__ csr,
                                             const float* __restrict__ aggE,
                                             const float* __restrict__ eWl,
                                             const float* __restrict__ ebl) {
    int wid = (blockIdx.x * 256 + threadIdx.x) >> 6;
    int lane = threadIdx.x & 63;
    if (wid >= N_NODES) return;
    int n = wid;
    int lg = lane >> 4, lq = lane & 15;
    const float4* h4 = (const float4*)h;
    int j0 = rowstart[n], j1 = rowstart[n + 1];
    float4 acc = make_float4(0.f, 0.f, 0.f, 0.f);
    int j = j0;
    while (j < j1) {
        int take = j1 - j;
        if (take > 64) take = 64;
        int myid = (lane < take) ? csr[j + lane] : 0;
        int nt = (take + 3) >> 2;
        int t = 0;
        for (; t + 4 <= nt; t += 4) {
            int e0 = t * 4 + lg, e1 = e0 + 4, e2 = e0 + 8, e3 = e0 + 12;
            int s0 = __shfl(myid, e0), s1 = __shfl(myid, e1),
                s2 = __shfl(myid, e2), s3 = __shfl(myid, e3);
            float4 v0 = h4[(size_t)s0 * 16 + lq];
            float4 v1 = h4[(size_t)s1 * 16 + lq];
            float4 v2 = h4[(size_t)s2 * 16 + lq];
            float4 v3 = h4[(size_t)s3 * 16 + lq];
            if (e0 < take) { acc.x += v0.x; acc.y += v0.y; acc.z += v0.z; acc.w += v0.w; }
            if (e1 < take) { acc.x += v1.x; acc.y += v1.y; acc.z += v1.z; acc.w += v1.w; }
            if (e2 < take) { acc.x += v2.x; acc.y += v2.y; acc.z += v2.z; acc.w += v2.w; }
            if (e3 < take) { acc.x += v3.x; acc.y += v3.y; acc.z += v3.z; acc.w += v3.w; }
        }
        for (; t < nt; ++t) {
            int e = t * 4 + lg;
            int s = __shfl(myid, e);
            float4 v = h4[(size_t)s * 16 + lq];
            if (e < take) { acc.x += v.x; acc.y += v.y; acc.z += v.z; acc.w += v.w; }
        }
        j += take;
    }
    // reduce the 4 edge-slot groups (same features, disjoint edges)
    acc.x += __shfl_xor(acc.x, 16); acc.y += __shfl_xor(acc.y, 16);
    acc.z += __shfl_xor(acc.z, 16); acc.w += __shfl_xor(acc.w, 16);
    acc.x += __shfl_xor(acc.x, 32); acc.y += __shfl_xor(acc.y, 32);
    acc.z += __shfl_xor(acc.z, 32); acc.w += __shfl_xor(acc.w, 32);
    // base terms
    const float4* eW4 = (const float4*)eWl;
    float4 ew0 = eW4[lq], ew1 = eW4[16 + lq], ew2 = eW4[32 + lq],
           ew3 = eW4[48 + lq], ew4 = eW4[64 + lq];
    float4 eb4 = ((const float4*)ebl)[lq];
    float a0 = aggE[n * 5 + 0], a1 = aggE[n * 5 + 1], a2 = aggE[n * 5 + 2],
          a3 = aggE[n * 5 + 3], a4 = aggE[n * 5 + 4];
    float c0 = a0 + 8.f;                       // self-loop attr [8,0,0,0,0]
    float ce = (float)(j1 - j0) + 1.f;         // eb per in-edge + self term
    float4 b = h4[(size_t)n * 16 + lq];
    b.x = fmaf(c0, ew0.x, b.x); b.y = fmaf(c0, ew0.y, b.y);
    b.z = fmaf(c0, ew0.z, b.z); b.w = fmaf(c0, ew0.w, b.w);
    b.x = fmaf(a1, ew1.x, b.x); b.y = fmaf(a1, ew1.y, b.y);
    b.z = fmaf(a1, ew1.z, b.z); b.w = fmaf(a1, ew1.w, b.w);
    b.x = fmaf(a2, ew2.x, b.x); b.y = fmaf(a2, ew2.y, b.y);
    b.z = fmaf(a2, ew2.z, b.z); b.w = fmaf(a2, ew2.w, b.w);
    b.x = fmaf(a3, ew3.x, b.x); b.y = fmaf(a3, ew3.y, b.y);
    b.z = fmaf(a3, ew3.z, b.z); b.w = fmaf(a3, ew3.w, b.w);
    b.x = fmaf(a4, ew4.x, b.x); b.y = fmaf(a4, ew4.y, b.y);
    b.z = fmaf(a4, ew4.z, b.z); b.w = fmaf(a4, ew4.w, b.w);
    b.x = fmaf(ce, eb4.x, b.x); b.y = fmaf(ce, eb4.y, b.y);
    b.z = fmaf(ce, eb4.z, b.z); b.w = fmaf(ce, eb4.w, b.w);
    if (lg == 0) {
        ((float4*)agg)[(size_t)n * 16 + lq] =
            make_float4(acc.x + b.x, acc.y + b.y, acc.z + b.z, acc.w + b.w);
    }
}

// hidden = relu(agg @ W1 + b1)   tile: 32 nodes x 128 hid, 4x4 per thread
__global__ __launch_bounds__(256) void k_mlp1(const float* __restrict__ agg,
                                              float* __restrict__ hidden,
                                              const float* __restrict__ W1l,
                                              const float* __restrict__ b1l) {
    __shared__ float w1s[64 * 128];
    __shared__ float as[32 * 68];
    __shared__ float b1s[128];
    int tid = threadIdx.x;
    int n0 = blockIdx.x * 32;
    const float4* wg = (const float4*)W1l;
    float4* wsh = (float4*)w1s;
#pragma unroll
    for (int i = 0; i < 8; ++i) wsh[tid + i * 256] = wg[tid + i * 256];
    if (tid < 128) b1s[tid] = b1l[tid];
    const float4* ag4 = (const float4*)agg;
#pragma unroll
    for (int i = 0; i < 2; ++i) {
        int idx = tid + i * 256;
        int m = idx >> 4, kq = idx & 15;
        int nn = n0 + m;
        float4 v = make_float4(0.f, 0.f, 0.f, 0.f);
        if (nn < N_NODES) v = ag4[nn * 16 + kq];
        *(float4*)&as[m * 68 + kq * 4] = v;
    }
    __syncthreads();
    int j0 = (tid & 31) * 4;
    int m0 = (tid >> 5) * 4;
    float acc[4][4] = {};
#pragma unroll 8
    for (int k = 0; k < 64; ++k) {
        float4 w = *(const float4*)&w1s[k * 128 + j0];
        float a0 = as[(m0 + 0) * 68 + k];
        float a1 = as[(m0 + 1) * 68 + k];
        float a2 = as[(m0 + 2) * 68 + k];
        float a3 = as[(m0 + 3) * 68 + k];
        acc[0][0] = fmaf(a0, w.x, acc[0][0]); acc[0][1] = fmaf(a0, w.y, acc[0][1]);
        acc[0][2] = fmaf(a0, w.z, acc[0][2]); acc[0][3] = fmaf(a0, w.w, acc[0][3]);
        acc[1][0] = fmaf(a1, w.x, acc[1][0]); acc[1][1] = fmaf(a1, w.y, acc[1][1]);
        acc[1][2] = fmaf(a1, w.z, acc[1][2]); acc[1][3] = fmaf(a1, w.w, acc[1][3]);
        acc[2][0] = fmaf(a2, w.x, acc[2][0]); acc[2][1] = fmaf(a2, w.y, acc[2][1]);
        acc[2][2] = fmaf(a2, w.z, acc[2][2]); acc[2][3] = fmaf(a2, w.w, acc[2][3]);
        acc[3][0] = fmaf(a3, w.x, acc[3][0]); acc[3][1] = fmaf(a3, w.y, acc[3][1]);
        acc[3][2] = fmaf(a3, w.z, acc[3][2]); acc[3][3] = fmaf(a3, w.w, acc[3][3]);
    }
#pragma unroll
    for (int a = 0; a < 4; ++a) {
        int nn = n0 + m0 + a;
        if (nn < N_NODES) {
            float4 o;
            o.x = fmaxf(acc[a][0] + b1s[j0 + 0], 0.f);
            o.y = fmaxf(acc[a][1] + b1s[j0 + 1], 0.f);
            o.z = fmaxf(acc[a][2] + b1s[j0 + 2], 0.f);
            o.w = fmaxf(acc[a][3] + b1s[j0 + 3], 0.f);
            *(float4*)&hidden[nn * HID + j0] = o;
        }
    }
}

// h2 = hidden @ W2 + b2, PLUS fused BN-stats reduction
__global__ __launch_bounds__(256) void k_mlp2(const float* __restrict__ hidden,
                                              float* __restrict__ h2,
                                              const float* __restrict__ W2l,
                                              const float* __restrict__ b2l,
                                              float* __restrict__ stats) {
    __shared__ float w2s[128 * 64];
    __shared__ float hs[64 * 132];
    __shared__ float b2s[64];
    int tid = threadIdx.x;
    int n0 = blockIdx.x * 64;
    const float4* wg = (const float4*)W2l;
    float4* wsh = (float4*)w2s;
#pragma unroll
    for (int i = 0; i < 8; ++i) wsh[tid + i * 256] = wg[tid + i * 256];
    if (tid < 64) b2s[tid] = b2l[tid];
    const float4* hg4 = (const float4*)hidden;
#pragma unroll
    for (int i = 0; i < 8; ++i) {
        int idx = tid + i * 256;
        int m = idx >> 5, kq = idx & 31;
        int nn = n0 + m;
        float4 v = make_float4(0.f, 0.f, 0.f, 0.f);
        if (nn < N_NODES) v = hg4[nn * 32 + kq];
        *(float4*)&hs[m * 132 + kq * 4] = v;
    }
    __syncthreads();
    int f0 = (tid & 15) * 4;
    int m0 = (tid >> 4) * 4;
    float acc[4][4] = {};
#pragma unroll 8
    for (int k = 0; k < 128; ++k) {
        float4 w = *(const float4*)&w2s[k * 64 + f0];
        float a0 = hs[(m0 + 0) * 132 + k];
        float a1 = hs[(m0 + 1) * 132 + k];
        float a2 = hs[(m0 + 2) * 132 + k];
        float a3 = hs[(m0 + 3) * 132 + k];
        acc[0][0] = fmaf(a0, w.x, acc[0][0]); acc[0][1] = fmaf(a0, w.y, acc[0][1]);
        acc[0][2] = fmaf(a0, w.z, acc[0][2]); acc[0][3] = fmaf(a0, w.w, acc[0][3]);
        acc[1][0] = fmaf(a1, w.x, acc[1][0]); acc[1][1] = fmaf(a1, w.y, acc[1][1]);
        acc[1][2] = fmaf(a1, w.z, acc[1][2]); acc[1][3] = fmaf(a1, w.w, acc[1][3]);
        acc[2][0] = fmaf(a2, w.x, acc[2][0]); acc[2][1] = fmaf(a2, w.y, acc[2][1]);
        acc[2][2] = fmaf(a2, w.z, acc[2][2]); acc[2][3] = fmaf(a2, w.w, acc[2][3]);
        acc[3][0] = fmaf(a3, w.x, acc[3][0]); acc[3][1] = fmaf(a3, w.y, acc[3][1]);
        acc[3][2] = fmaf(a3, w.z, acc[3][2]); acc[3][3] = fmaf(a3, w.w, acc[3][3]);
    }
    float sf[4] = {0.f, 0.f, 0.f, 0.f}, qf[4] = {0.f, 0.f, 0.f, 0.f};
#pragma unroll
    for (int a = 0; a < 4; ++a) {
        int nn = n0 + m0 + a;
        if (nn < N_NODES) {
            float v0 = acc[a][0] + b2s[f0 + 0];
            float v1 = acc[a][1] + b2s[f0 + 1];
            float v2 = acc[a][2] + b2s[f0 + 2];
            float v3 = acc[a][3] + b2s[f0 + 3];
            *(float4*)&h2[nn * EMB + f0] = make_float4(v0, v1, v2, v3);
            sf[0] += v0; sf[1] += v1; sf[2] += v2; sf[3] += v3;
            qf[0] = fmaf(v0, v0, qf[0]); qf[1] = fmaf(v1, v1, qf[1]);
            qf[2] = fmaf(v2, v2, qf[2]); qf[3] = fmaf(v3, v3, qf[3]);
        }
    }
    __syncthreads();
    float* red = hs;
    int mg = tid >> 4;
#pragma unroll
    for (int j = 0; j < 4; ++j) {
        red[mg * 64 + f0 + j] = sf[j];
        red[1024 + mg * 64 + f0 + j] = qf[j];
    }
    __syncthreads();
    if (tid < 64) {
        float s = 0.f, q = 0.f;
#pragma unroll
        for (int m = 0; m < 16; ++m) {
            s += red[m * 64 + tid];
            q += red[1024 + m * 64 + tid];
        }
        atomAddF(&stats[tid], s);
        atomAddF(&stats[64 + tid], q);
    }
}

// BN apply + ELU (layers 0,1)
__global__ void k_bn(const float* __restrict__ h2, float* __restrict__ h,
                     const float* __restrict__ stats, const float* __restrict__ gam,
                     const float* __restrict__ bet) {
    int gid = blockIdx.x * 256 + threadIdx.x;
    if (gid >= N_NODES * EMB) return;
    int f = gid & 63;
    const float invN = 1.f / (float)N_NODES;
    float mean = stats[f] * invN;
    float var = stats[64 + f] * invN - mean * mean;
    float inv = rsqrtf(var + BN_EPS);
    float v = (h2[gid] - mean) * inv * gam[f] + bet[f];
    h[gid] = v > 0.f ? v : expm1f(v);
}

// last layer: BN only for the 250 super-nodes, straight to out (saves a 25.6MB pass)
__global__ void k_bnout(const float* __restrict__ h2, const int* __restrict__ last,
                        const float* __restrict__ stats, const float* __restrict__ gam,
                        const float* __restrict__ bet, float* __restrict__ out) {
    int gid = blockIdx.x * 256 + threadIdx.x;
    if (gid >= NGRAPH * EMB) return;
    int b = gid >> 6, f = gid & 63;
    const float invN = 1.f / (float)N_NODES;
    float mean = stats[f] * invN;
    float var = stats[64 + f] * invN - mean * mean;
    float inv = rsqrtf(var + BN_EPS);
    out[gid] = (h2[last[b] * EMB + f] - mean) * inv * gam[f] + bet[f];
}

extern "C" void kernel_launch(void* const* d_in, const int* in_sizes, int n_in,
                              void* d_out, int out_size, void* d_ws, size_t ws_size,
                              hipStream_t stream) {
    const float* x   = (const float*)d_in[0];
    const float* ea  = (const float*)d_in[1];
    const int*   eidx= (const int*)d_in[2];
    const int*   last= (const int*)d_in[3];
    const float* xW  = (const float*)d_in[4];
    const float* xb  = (const float*)d_in[5];
    const float* eW  = (const float*)d_in[6];
    const float* eb  = (const float*)d_in[7];
    const float* W1  = (const float*)d_in[8];
    const float* b1  = (const float*)d_in[9];
    const float* W2  = (const float*)d_in[10];
    const float* b2  = (const float*)d_in[11];
    const float* gam = (const float*)d_in[12];
    const float* bet = (const float*)d_in[13];
    float* out = (float*)d_out;

    const int* srcI = eidx;
    const int* dstI = eidx + N_EDGES;

    float* h      = (float*)d_ws;              // N*64
    float* agg    = h + N_NODES * EMB;         // N*64 (reused as h2)
    float* hidden = agg + N_NODES * EMB;       // N*128
    float* aggE   = hidden + N_NODES * HID;    // N*5
    float* stats  = aggE + N_NODES * EFD;      // L*128
    int* deg      = (int*)(stats + NLAYER * 2 * EMB);  // N
    int* rowstart = deg + N_NODES;             // N+1
    int* cursor   = rowstart + N_NODES + 1;    // N
    int* csr      = cursor + N_NODES;          // E (permanent, src only)
    int* bsum     = csr + N_EDGES;             // NB_SCAN
    int* boff     = bsum + NB_SCAN;            // NB_SCAN
    int2* csr2    = (int2*)hidden;             // E int2 = 8MB, alias (pre-loop only)

    hipMemsetAsync(deg, 0, N_NODES * sizeof(int), stream);
    hipMemsetAsync(stats, 0, NLAYER * 2 * EMB * sizeof(float), stream);

    k_input<<<(N_NODES * EMB + 255) / 256, 256, 0, stream>>>(x, xW, xb, h);
    k_hist<<<(N_EDGES + 255) / 256, 256, 0, stream>>>(dstI, deg);
    k_scanA<<<NB_SCAN, 256, 0, stream>>>(deg, bsum);
    k_scanB<<<1, 256, 0, stream>>>(bsum, boff);
    k_scanC<<<NB_SCAN, 256, 0, stream>>>(deg, boff, rowstart, cursor);
    k_fill<<<(N_EDGES + 255) / 256, 256, 0, stream>>>(srcI, dstI, cursor, csr2);
    k_aggE<<<(N_NODES * 64 + 255) / 256, 256, 0, stream>>>(rowstart, csr2, ea, aggE, csr);

    for (int l = 0; l < NLAYER; ++l) {
        k_agg<<<(N_NODES * 64 + 255) / 256, 256, 0, stream>>>(
            h, agg, rowstart, csr, aggE, eW + l * EFD * EMB, eb + l * EMB);
        k_mlp1<<<(N_NODES + 31) / 32, 256, 0, stream>>>(agg, hidden, W1 + l * EMB * HID,
                                                        b1 + l * HID);
        k_mlp2<<<(N_NODES + 63) / 64, 256, 0, stream>>>(hidden, agg, W2 + l * HID * EMB,
                                                        b2 + l * EMB, stats + l * 2 * EMB);
        if (l < NLAYER - 1) {
            k_bn<<<(N_NODES * EMB + 255) / 256, 256, 0, stream>>>(
                agg, h, stats + l * 2 * EMB, gam + l * EMB, bet + l * EMB);
        } else {
            k_bnout<<<(NGRAPH * EMB + 255) / 256, 256, 0, stream>>>(
                agg, last, stats + l * 2 * EMB, gam + l * EMB, bet + l * EMB, out);
        }
    }
}

// Round 5
// 430.387 us; speedup vs baseline: 1.1952x; 1.1952x over previous
//
#include <hip/hip_runtime.h>

#define N_NODES 50000
#define N_EDGES 1000000
#define EMB     64
#define HID     128
#define NLAYER  3
#define NGRAPH  250
#define XFD     7
#define EFD     5
#define BN_EPS  1e-5f

// two-level counting sort geometry
#define NBKT  196            // coarse buckets = dst>>8 (256 nodes each)
#define CHKE  4096           // edges per chunk
#define NCHK  245            // ceil(1e6/4096)
#define CNTM  (NBKT * NCHK)  // 48020 count-matrix entries
#define NB2   ((CNTM + 255) / 256)  // 188 scan blocks

__device__ __forceinline__ void atomAddF(float* p, float v) {
    __hip_atomic_fetch_add(p, v, __ATOMIC_RELAXED, __HIP_MEMORY_SCOPE_AGENT);
}

// h = x @ xW + xb
__global__ void k_input(const float* __restrict__ x, const float* __restrict__ xW,
                        const float* __restrict__ xb, float* __restrict__ h) {
    int gid = blockIdx.x * 256 + threadIdx.x;
    if (gid >= N_NODES * EMB) return;
    int n = gid >> 6, f = gid & 63;
    float acc = xb[f];
#pragma unroll
    for (int k = 0; k < XFD; ++k) acc = fmaf(x[n * XFD + k], xW[k * EMB + f], acc);
    h[gid] = acc;
}

// ---- counting-sort phase A: per-chunk coarse-bucket histogram ----
// (R4 lesson: random 8B scatter = 64MB line-touch writeback, 70us. Sort instead.)
__global__ __launch_bounds__(256) void k_binA(const int* __restrict__ dst,
                                              int* __restrict__ cntmat) {
    __shared__ int hist[NBKT];
    int tid = threadIdx.x, c = blockIdx.x;
    for (int i = tid; i < NBKT; i += 256) hist[i] = 0;
    __syncthreads();
    int e0 = c * CHKE, e1 = min(e0 + CHKE, N_EDGES);
    for (int i = e0 + tid; i < e1; i += 256) atomicAdd(&hist[dst[i] >> 8], 1);
    __syncthreads();
    for (int b = tid; b < NBKT; b += 256) cntmat[b * NCHK + c] = hist[b];  // bucket-major
}

// ---- generalized 3-phase multi-block exclusive scan ----
__global__ __launch_bounds__(256) void k_gscanA(const int* __restrict__ in, int n,
                                                int* __restrict__ bsum) {
    int tid = threadIdx.x, lane = tid & 63, wid = tid >> 6;
    int i = blockIdx.x * 256 + tid;
    int v = (i < n) ? in[i] : 0;
#pragma unroll
    for (int off = 32; off; off >>= 1) v += __shfl_down(v, off);
    __shared__ int ws[4];
    if (lane == 0) ws[wid] = v;
    __syncthreads();
    if (tid == 0) bsum[blockIdx.x] = ws[0] + ws[1] + ws[2] + ws[3];
}

__global__ __launch_bounds__(256) void k_gscanB(const int* __restrict__ bsum, int nb,
                                                int* __restrict__ boff) {
    int tid = threadIdx.x, lane = tid & 63, wid = tid >> 6;
    int v = (tid < nb) ? bsum[tid] : 0;
    int x = v;
#pragma unroll
    for (int off = 1; off < 64; off <<= 1) {
        int y = __shfl_up(x, off);
        if (lane >= off) x += y;
    }
    __shared__ int wtot[4];
    if (lane == 63) wtot[wid] = x;
    __syncthreads();
    int woff = 0;
    for (int w = 0; w < wid; ++w) woff += wtot[w];
    if (tid < nb) boff[tid] = woff + x - v;
}

__global__ __launch_bounds__(256) void k_gscanC(const int* __restrict__ in, int n,
                                                const int* __restrict__ boff,
                                                int* __restrict__ out) {
    int tid = threadIdx.x, lane = tid & 63, wid = tid >> 6;
    int i = blockIdx.x * 256 + tid;
    int v = (i < n) ? in[i] : 0;
    int x = v;
#pragma unroll
    for (int off = 1; off < 64; off <<= 1) {
        int y = __shfl_up(x, off);
        if (lane >= off) x += y;
    }
    __shared__ int wtot[4];
    if (lane == 63) wtot[wid] = x;
    __syncthreads();
    int woff = boff[blockIdx.x];
    for (int w = 0; w < wid; ++w) woff += wtot[w];
    if (i < n) out[i] = woff + x - v;
}

// ---- phase C: coarse scatter into per-(bucket,chunk) contiguous runs ----
__global__ __launch_bounds__(256) void k_binC(const int* __restrict__ src,
                                              const int* __restrict__ dst,
                                              const int* __restrict__ off2,
                                              int4* __restrict__ buf) {
    __shared__ int cur[NBKT];
    int tid = threadIdx.x, c = blockIdx.x;
    for (int b = tid; b < NBKT; b += 256) cur[b] = off2[b * NCHK + c];
    __syncthreads();
    int e0 = c * CHKE, e1 = min(e0 + CHKE, N_EDGES);
    for (int i = e0 + tid; i < e1; i += 256) {
        int d = dst[i];
        int b = d >> 8;
        int p = atomicAdd(&cur[b], 1);
        buf[p] = make_int4(src[i], i, d, 0);
    }
}

// ---- phase D: per-bucket fine counting sort -> csr + rowstart + aggE ----
// One block per bucket (256 dst values, ~5100 contiguous edges). All csr writes
// block-local contiguous; aggE accumulated via LDS float atomics (absorbs k_aggE).
__global__ __launch_bounds__(256) void k_binD(const int4* __restrict__ buf,
                                              const int* __restrict__ off2,
                                              const float* __restrict__ ea,
                                              int* __restrict__ csr,
                                              int* __restrict__ rowstart,
                                              float* __restrict__ aggE) {
    __shared__ int hist[256];
    __shared__ int cur[256];
    __shared__ float accL[256 * EFD];
    __shared__ int wtot[4];
    int tid = threadIdx.x, b = blockIdx.x;
    int bstart = off2[b * NCHK];
    int bend = (b + 1 < NBKT) ? off2[(b + 1) * NCHK] : N_EDGES;
    hist[tid] = 0;
    for (int i = tid; i < 256 * EFD; i += 256) accL[i] = 0.f;
    __syncthreads();
    for (int j = bstart + tid; j < bend; j += 256) atomicAdd(&hist[buf[j].z & 255], 1);
    __syncthreads();
    // block exclusive scan of hist
    int lane = tid & 63, wid = tid >> 6;
    int v = hist[tid], x = v;
#pragma unroll
    for (int off = 1; off < 64; off <<= 1) {
        int y = __shfl_up(x, off);
        if (lane >= off) x += y;
    }
    if (lane == 63) wtot[wid] = x;
    __syncthreads();
    int woff = 0;
    for (int w = 0; w < wid; ++w) woff += wtot[w];
    int ex = woff + x - v;
    cur[tid] = ex;
    int node = b * 256 + tid;
    if (node < N_NODES) rowstart[node] = bstart + ex;
    if (b == NBKT - 1 && tid == 255) rowstart[N_NODES] = N_EDGES;
    __syncthreads();
    // fine scatter (contiguous within bucket) + edge-attr accumulation
    for (int j = bstart + tid; j < bend; j += 256) {
        int4 t = buf[j];
        int local = t.z & 255;
        int p = atomicAdd(&cur[local], 1);
        csr[bstart + p] = t.x;
        const float* pe = ea + (size_t)t.y * EFD;
        atomicAdd(&accL[local * EFD + 0], pe[0]);
        atomicAdd(&accL[local * EFD + 1], pe[1]);
        atomicAdd(&accL[local * EFD + 2], pe[2]);
        atomicAdd(&accL[local * EFD + 3], pe[3]);
        atomicAdd(&accL[local * EFD + 4], pe[4]);
    }
    __syncthreads();
    int validN = min(256, N_NODES - b * 256);
    for (int i = tid; i < validN * EFD; i += 256)
        aggE[(size_t)b * 256 * EFD + i] = accL[i];
}

// agg[n] = h[n] + (8*eW[0]+eb) + sum_in h[src] + aggE[n]@eW + deg*eb
// wave/node, float4 gathers, 4 edges in flight
__global__ __launch_bounds__(256) void k_agg(const float* __restrict__ h,
                                             float* __restrict__ agg,
                                             const int* __restrict__ rowstart,
                                             const int* __restrict__ csr,
                                             const float* __restrict__ aggE,
                                             const float* __restrict__ eWl,
                                             const float* __restrict__ ebl) {
    int wid = (blockIdx.x * 256 + threadIdx.x) >> 6;
    int lane = threadIdx.x & 63;
    if (wid >= N_NODES) return;
    int n = wid;
    int lg = lane >> 4, lq = lane & 15;
    const float4* h4 = (const float4*)h;
    int j0 = rowstart[n], j1 = rowstart[n + 1];
    float4 acc = make_float4(0.f, 0.f, 0.f, 0.f);
    int j = j0;
    while (j < j1) {
        int take = j1 - j;
        if (take > 64) take = 64;
        int myid = (lane < take) ? csr[j + lane] : 0;
        int nt = (take + 3) >> 2;
        int t = 0;
        for (; t + 4 <= nt; t += 4) {
            int e0 = t * 4 + lg, e1 = e0 + 4, e2 = e0 + 8, e3 = e0 + 12;
            int s0 = __shfl(myid, e0), s1 = __shfl(myid, e1),
                s2 = __shfl(myid, e2), s3 = __shfl(myid, e3);
            float4 v0 = h4[(size_t)s0 * 16 + lq];
            float4 v1 = h4[(size_t)s1 * 16 + lq];
            float4 v2 = h4[(size_t)s2 * 16 + lq];
            float4 v3 = h4[(size_t)s3 * 16 + lq];
            if (e0 < take) { acc.x += v0.x; acc.y += v0.y; acc.z += v0.z; acc.w += v0.w; }
            if (e1 < take) { acc.x += v1.x; acc.y += v1.y; acc.z += v1.z; acc.w += v1.w; }
            if (e2 < take) { acc.x += v2.x; acc.y += v2.y; acc.z += v2.z; acc.w += v2.w; }
            if (e3 < take) { acc.x += v3.x; acc.y += v3.y; acc.z += v3.z; acc.w += v3.w; }
        }
        for (; t < nt; ++t) {
            int e = t * 4 + lg;
            int s = __shfl(myid, e);
            float4 v = h4[(size_t)s * 16 + lq];
            if (e < take) { acc.x += v.x; acc.y += v.y; acc.z += v.z; acc.w += v.w; }
        }
        j += take;
    }
    acc.x += __shfl_xor(acc.x, 16); acc.y += __shfl_xor(acc.y, 16);
    acc.z += __shfl_xor(acc.z, 16); acc.w += __shfl_xor(acc.w, 16);
    acc.x += __shfl_xor(acc.x, 32); acc.y += __shfl_xor(acc.y, 32);
    acc.z += __shfl_xor(acc.z, 32); acc.w += __shfl_xor(acc.w, 32);
    const float4* eW4 = (const float4*)eWl;
    float4 ew0 = eW4[lq], ew1 = eW4[16 + lq], ew2 = eW4[32 + lq],
           ew3 = eW4[48 + lq], ew4 = eW4[64 + lq];
    float4 eb4 = ((const float4*)ebl)[lq];
    float a0 = aggE[n * 5 + 0], a1 = aggE[n * 5 + 1], a2 = aggE[n * 5 + 2],
          a3 = aggE[n * 5 + 3], a4 = aggE[n * 5 + 4];
    float c0 = a0 + 8.f;
    float ce = (float)(j1 - j0) + 1.f;
    float4 bb = h4[(size_t)n * 16 + lq];
    bb.x = fmaf(c0, ew0.x, bb.x); bb.y = fmaf(c0, ew0.y, bb.y);
    bb.z = fmaf(c0, ew0.z, bb.z); bb.w = fmaf(c0, ew0.w, bb.w);
    bb.x = fmaf(a1, ew1.x, bb.x); bb.y = fmaf(a1, ew1.y, bb.y);
    bb.z = fmaf(a1, ew1.z, bb.z); bb.w = fmaf(a1, ew1.w, bb.w);
    bb.x = fmaf(a2, ew2.x, bb.x); bb.y = fmaf(a2, ew2.y, bb.y);
    bb.z = fmaf(a2, ew2.z, bb.z); bb.w = fmaf(a2, ew2.w, bb.w);
    bb.x = fmaf(a3, ew3.x, bb.x); bb.y = fmaf(a3, ew3.y, bb.y);
    bb.z = fmaf(a3, ew3.z, bb.z); bb.w = fmaf(a3, ew3.w, bb.w);
    bb.x = fmaf(a4, ew4.x, bb.x); bb.y = fmaf(a4, ew4.y, bb.y);
    bb.z = fmaf(a4, ew4.z, bb.z); bb.w = fmaf(a4, ew4.w, bb.w);
    bb.x = fmaf(ce, eb4.x, bb.x); bb.y = fmaf(ce, eb4.y, bb.y);
    bb.z = fmaf(ce, eb4.z, bb.z); bb.w = fmaf(ce, eb4.w, bb.w);
    if (lg == 0) {
        ((float4*)agg)[(size_t)n * 16 + lq] =
            make_float4(acc.x + bb.x, acc.y + bb.y, acc.z + bb.z, acc.w + bb.w);
    }
}

// hidden = relu(agg @ W1 + b1)   tile: 32 nodes x 128 hid, 4x4 per thread
__global__ __launch_bounds__(256) void k_mlp1(const float* __restrict__ agg,
                                              float* __restrict__ hidden,
                                              const float* __restrict__ W1l,
                                              const float* __restrict__ b1l) {
    __shared__ float w1s[64 * 128];
    __shared__ float as[32 * 68];
    __shared__ float b1s[128];
    int tid = threadIdx.x;
    int n0 = blockIdx.x * 32;
    const float4* wg = (const float4*)W1l;
    float4* wsh = (float4*)w1s;
#pragma unroll
    for (int i = 0; i < 8; ++i) wsh[tid + i * 256] = wg[tid + i * 256];
    if (tid < 128) b1s[tid] = b1l[tid];
    const float4* ag4 = (const float4*)agg;
#pragma unroll
    for (int i = 0; i < 2; ++i) {
        int idx = tid + i * 256;
        int m = idx >> 4, kq = idx & 15;
        int nn = n0 + m;
        float4 v = make_float4(0.f, 0.f, 0.f, 0.f);
        if (nn < N_NODES) v = ag4[nn * 16 + kq];
        *(float4*)&as[m * 68 + kq * 4] = v;
    }
    __syncthreads();
    int j0 = (tid & 31) * 4;
    int m0 = (tid >> 5) * 4;
    float acc[4][4] = {};
#pragma unroll 8
    for (int k = 0; k < 64; ++k) {
        float4 w = *(const float4*)&w1s[k * 128 + j0];
        float a0 = as[(m0 + 0) * 68 + k];
        float a1 = as[(m0 + 1) * 68 + k];
        float a2 = as[(m0 + 2) * 68 + k];
        float a3 = as[(m0 + 3) * 68 + k];
        acc[0][0] = fmaf(a0, w.x, acc[0][0]); acc[0][1] = fmaf(a0, w.y, acc[0][1]);
        acc[0][2] = fmaf(a0, w.z, acc[0][2]); acc[0][3] = fmaf(a0, w.w, acc[0][3]);
        acc[1][0] = fmaf(a1, w.x, acc[1][0]); acc[1][1] = fmaf(a1, w.y, acc[1][1]);
        acc[1][2] = fmaf(a1, w.z, acc[1][2]); acc[1][3] = fmaf(a1, w.w, acc[1][3]);
        acc[2][0] = fmaf(a2, w.x, acc[2][0]); acc[2][1] = fmaf(a2, w.y, acc[2][1]);
        acc[2][2] = fmaf(a2, w.z, acc[2][2]); acc[2][3] = fmaf(a2, w.w, acc[2][3]);
        acc[3][0] = fmaf(a3, w.x, acc[3][0]); acc[3][1] = fmaf(a3, w.y, acc[3][1]);
        acc[3][2] = fmaf(a3, w.z, acc[3][2]); acc[3][3] = fmaf(a3, w.w, acc[3][3]);
    }
#pragma unroll
    for (int a = 0; a < 4; ++a) {
        int nn = n0 + m0 + a;
        if (nn < N_NODES) {
            float4 o;
            o.x = fmaxf(acc[a][0] + b1s[j0 + 0], 0.f);
            o.y = fmaxf(acc[a][1] + b1s[j0 + 1], 0.f);
            o.z = fmaxf(acc[a][2] + b1s[j0 + 2], 0.f);
            o.w = fmaxf(acc[a][3] + b1s[j0 + 3], 0.f);
            *(float4*)&hidden[nn * HID + j0] = o;
        }
    }
}

// h2 = hidden @ W2 + b2, PLUS fused BN-stats reduction
__global__ __launch_bounds__(256) void k_mlp2(const float* __restrict__ hidden,
                                              float* __restrict__ h2,
                                              const float* __restrict__ W2l,
                                              const float* __restrict__ b2l,
                                              float* __restrict__ stats) {
    __shared__ float w2s[128 * 64];
    __shared__ float hs[64 * 132];
    __shared__ float b2s[64];
    int tid = threadIdx.x;
    int n0 = blockIdx.x * 64;
    const float4* wg = (const float4*)W2l;
    float4* wsh = (float4*)w2s;
#pragma unroll
    for (int i = 0; i < 8; ++i) wsh[tid + i * 256] = wg[tid + i * 256];
    if (tid < 64) b2s[tid] = b2l[tid];
    const float4* hg4 = (const float4*)hidden;
#pragma unroll
    for (int i = 0; i < 8; ++i) {
        int idx = tid + i * 256;
        int m = idx >> 5, kq = idx & 31;
        int nn = n0 + m;
        float4 v = make_float4(0.f, 0.f, 0.f, 0.f);
        if (nn < N_NODES) v = hg4[nn * 32 + kq];
        *(float4*)&hs[m * 132 + kq * 4] = v;
    }
    __syncthreads();
    int f0 = (tid & 15) * 4;
    int m0 = (tid >> 4) * 4;
    float acc[4][4] = {};
#pragma unroll 8
    for (int k = 0; k < 128; ++k) {
        float4 w = *(const float4*)&w2s[k * 64 + f0];
        float a0 = hs[(m0 + 0) * 132 + k];
        float a1 = hs[(m0 + 1) * 132 + k];
        float a2 = hs[(m0 + 2) * 132 + k];
        float a3 = hs[(m0 + 3) * 132 + k];
        acc[0][0] = fmaf(a0, w.x, acc[0][0]); acc[0][1] = fmaf(a0, w.y, acc[0][1]);
        acc[0][2] = fmaf(a0, w.z, acc[0][2]); acc[0][3] = fmaf(a0, w.w, acc[0][3]);
        acc[1][0] = fmaf(a1, w.x, acc[1][0]); acc[1][1] = fmaf(a1, w.y, acc[1][1]);
        acc[1][2] = fmaf(a1, w.z, acc[1][2]); acc[1][3] = fmaf(a1, w.w, acc[1][3]);
        acc[2][0] = fmaf(a2, w.x, acc[2][0]); acc[2][1] = fmaf(a2, w.y, acc[2][1]);
        acc[2][2] = fmaf(a2, w.z, acc[2][2]); acc[2][3] = fmaf(a2, w.w, acc[2][3]);
        acc[3][0] = fmaf(a3, w.x, acc[3][0]); acc[3][1] = fmaf(a3, w.y, acc[3][1]);
        acc[3][2] = fmaf(a3, w.z, acc[3][2]); acc[3][3] = fmaf(a3, w.w, acc[3][3]);
    }
    float sf[4] = {0.f, 0.f, 0.f, 0.f}, qf[4] = {0.f, 0.f, 0.f, 0.f};
#pragma unroll
    for (int a = 0; a < 4; ++a) {
        int nn = n0 + m0 + a;
        if (nn < N_NODES) {
            float v0 = acc[a][0] + b2s[f0 + 0];
            float v1 = acc[a][1] + b2s[f0 + 1];
            float v2 = acc[a][2] + b2s[f0 + 2];
            float v3 = acc[a][3] + b2s[f0 + 3];
            *(float4*)&h2[nn * EMB + f0] = make_float4(v0, v1, v2, v3);
            sf[0] += v0; sf[1] += v1; sf[2] += v2; sf[3] += v3;
            qf[0] = fmaf(v0, v0, qf[0]); qf[1] = fmaf(v1, v1, qf[1]);
            qf[2] = fmaf(v2, v2, qf[2]); qf[3] = fmaf(v3, v3, qf[3]);
        }
    }
    __syncthreads();
    float* red = hs;
    int mg = tid >> 4;
#pragma unroll
    for (int j = 0; j < 4; ++j) {
        red[mg * 64 + f0 + j] = sf[j];
        red[1024 + mg * 64 + f0 + j] = qf[j];
    }
    __syncthreads();
    if (tid < 64) {
        float s = 0.f, q = 0.f;
#pragma unroll
        for (int m = 0; m < 16; ++m) {
            s += red[m * 64 + tid];
            q += red[1024 + m * 64 + tid];
        }
        atomAddF(&stats[tid], s);
        atomAddF(&stats[64 + tid], q);
    }
}

// BN apply + ELU (layers 0,1)
__global__ void k_bn(const float* __restrict__ h2, float* __restrict__ h,
                     const float* __restrict__ stats, const float* __restrict__ gam,
                     const float* __restrict__ bet) {
    int gid = blockIdx.x * 256 + threadIdx.x;
    if (gid >= N_NODES * EMB) return;
    int f = gid & 63;
    const float invN = 1.f / (float)N_NODES;
    float mean = stats[f] * invN;
    float var = stats[64 + f] * invN - mean * mean;
    float inv = rsqrtf(var + BN_EPS);
    float v = (h2[gid] - mean) * inv * gam[f] + bet[f];
    h[gid] = v > 0.f ? v : expm1f(v);
}

// last layer: BN only for the 250 super-nodes, straight to out
__global__ void k_bnout(const float* __restrict__ h2, const int* __restrict__ last,
                        const float* __restrict__ stats, const float* __restrict__ gam,
                        const float* __restrict__ bet, float* __restrict__ out) {
    int gid = blockIdx.x * 256 + threadIdx.x;
    if (gid >= NGRAPH * EMB) return;
    int b = gid >> 6, f = gid & 63;
    const float invN = 1.f / (float)N_NODES;
    float mean = stats[f] * invN;
    float var = stats[64 + f] * invN - mean * mean;
    float inv = rsqrtf(var + BN_EPS);
    out[gid] = (h2[last[b] * EMB + f] - mean) * inv * gam[f] + bet[f];
}

extern "C" void kernel_launch(void* const* d_in, const int* in_sizes, int n_in,
                              void* d_out, int out_size, void* d_ws, size_t ws_size,
                              hipStream_t stream) {
    const float* x   = (const float*)d_in[0];
    const float* ea  = (const float*)d_in[1];
    const int*   eidx= (const int*)d_in[2];
    const int*   last= (const int*)d_in[3];
    const float* xW  = (const float*)d_in[4];
    const float* xb  = (const float*)d_in[5];
    const float* eW  = (const float*)d_in[6];
    const float* eb  = (const float*)d_in[7];
    const float* W1  = (const float*)d_in[8];
    const float* b1  = (const float*)d_in[9];
    const float* W2  = (const float*)d_in[10];
    const float* b2  = (const float*)d_in[11];
    const float* gam = (const float*)d_in[12];
    const float* bet = (const float*)d_in[13];
    float* out = (float*)d_out;

    const int* srcI = eidx;
    const int* dstI = eidx + N_EDGES;

    float* h      = (float*)d_ws;              // N*64
    float* agg    = h + N_NODES * EMB;         // N*64 (reused as h2)
    float* hidden = agg + N_NODES * EMB;       // N*128 (25.6MB)
    float* aggE   = hidden + N_NODES * HID;    // N*5
    float* stats  = aggE + N_NODES * EFD;      // L*128
    int* rowstart = (int*)(stats + NLAYER * 2 * EMB);  // N+1
    int* csr      = rowstart + N_NODES + 1;    // E (final, src sorted by dst)
    int* cntmat   = csr + N_EDGES;             // CNTM
    int* off2     = cntmat + CNTM;             // CNTM
    int* bsum     = off2 + CNTM;               // NB2
    int* boff     = bsum + NB2;                // NB2
    int4* buf     = (int4*)hidden;             // E int4 = 16MB, alias (pre-loop only)

    hipMemsetAsync(stats, 0, NLAYER * 2 * EMB * sizeof(float), stream);

    k_input<<<(N_NODES * EMB + 255) / 256, 256, 0, stream>>>(x, xW, xb, h);
    k_binA<<<NCHK, 256, 0, stream>>>(dstI, cntmat);
    k_gscanA<<<NB2, 256, 0, stream>>>(cntmat, CNTM, bsum);
    k_gscanB<<<1, 256, 0, stream>>>(bsum, NB2, boff);
    k_gscanC<<<NB2, 256, 0, stream>>>(cntmat, CNTM, boff, off2);
    k_binC<<<NCHK, 256, 0, stream>>>(srcI, dstI, off2, buf);
    k_binD<<<NBKT, 256, 0, stream>>>(buf, off2, ea, csr, rowstart, aggE);

    for (int l = 0; l < NLAYER; ++l) {
        k_agg<<<(N_NODES * 64 + 255) / 256, 256, 0, stream>>>(
            h, agg, rowstart, csr, aggE, eW + l * EFD * EMB, eb + l * EMB);
        k_mlp1<<<(N_NODES + 31) / 32, 256, 0, stream>>>(agg, hidden, W1 + l * EMB * HID,
                                                        b1 + l * HID);
        k_mlp2<<<(N_NODES + 63) / 64, 256, 0, stream>>>(hidden, agg, W2 + l * HID * EMB,
                                                        b2 + l * EMB, stats + l * 2 * EMB);
        if (l < NLAYER - 1) {
            k_bn<<<(N_NODES * EMB + 255) / 256, 256, 0, stream>>>(
                agg, h, stats + l * 2 * EMB, gam + l * EMB, bet + l * EMB);
        } else {
            k_bnout<<<(NGRAPH * EMB + 255) / 256, 256, 0, stream>>>(
                agg, last, stats + l * 2 * EMB, gam + l * EMB, bet + l * EMB, out);
        }
    }
}